// Round 2
// baseline (7191330.469 us; speedup 1.0000x reference)
//
// LSTM_45337674776685 — R2: XCD-local scan sync.
// Scan now runs as 16 wgs x 4 waves self-claimed onto ONE XCD (via
// HW_REG_XCC_ID + atomic claim). Cross-wg h exchange through the XCD's L2:
// producers plain-store (writethrough), consumers sc0 loads (L1-bypass,
// L2-served, ~200cy instead of ~900cy MALL). Release reordered: h stores ->
// vmcnt(0) -> flag -> hist (nontemporal). Weights register-resident bf16 hi/lo,
// 3x mfma_f32_32x32x16_bf16 per k-tile (emulated fp32).

#include <hip/hip_runtime.h>
#include <stdint.h>

typedef unsigned short u16;
typedef unsigned int   u32;
typedef unsigned long long u64;

typedef short  bf16x8 __attribute__((ext_vector_type(8)));
typedef float  f32x16 __attribute__((ext_vector_type(16)));

#define DEVI static __device__ __forceinline__
#define NWG 16   // claimed wgs per scan (one XCD)

DEVI u16 f2bf(float x) {
  u32 u = __float_as_uint(x);
  u += 0x7FFFu + ((u >> 16) & 1u);
  return (u16)(u >> 16);
}
DEVI float bf2f(u16 h) { return __uint_as_float(((u32)h) << 16); }

DEVI float sig_fast(float x) {
  float d = 1.f + __expf(-x);
  float r = __builtin_amdgcn_rcpf(d);
  return r * (2.f - d * r);
}
DEVI float silu_f(float x) { return x * sig_fast(x); }

DEVI bf16x8 mk8(u64 a, u64 b) {
  union { u64 q[2]; bf16x8 v; } u;
  u.q[0] = a; u.q[1] = b;
  return u.v;
}

// sc0 loads: bypass L1, served by the XCD's L2 (SE scope) — coherent across
// wgs that share an XCD.
DEVI u32 poll_load_u32(const u32* p) {
  u32 v;
  asm volatile("global_load_dword %0, %1, off sc0\n\ts_waitcnt vmcnt(0)"
               : "=v"(v) : "v"(p) : "memory");
  return v;
}
DEVI u64 load_sc0_u64(const u16* p) {
  u64 v;
  asm volatile("global_load_dwordx2 %0, %1, off sc0" : "=v"(v) : "v"(p));
  return v;
}

// ---------------------------------------------------------------------------
// prep: pack W_hh0/1 into MFMA B-fragments, biases, flags, claim areas.
// ---------------------------------------------------------------------------
__global__ void k_prep(const float* __restrict__ Whh0, const float* __restrict__ Whh1,
                       const float* __restrict__ bih0, const float* __restrict__ bhh0,
                       const float* __restrict__ bih1, const float* __restrict__ bhh1,
                       u32* __restrict__ wf, float* __restrict__ biasc,
                       u32* __restrict__ flags, u32* __restrict__ claims)
{
  if (blockIdx.x < 256) {
    int g = blockIdx.x * 256 + threadIdx.x;
    int layer = g >> 15;
    int nt = (g >> 10) & 31;
    int kt = (g >> 6) & 15;
    int l  = g & 63;
    int rr = l & 31, gate = rr & 3, jj = rr >> 2;
    int r  = gate * 256 + nt * 8 + jj;
    int k0 = kt * 16 + (l >> 5) * 8;
    const float* W = layer ? Whh1 : Whh0;
    float v[8];
    #pragma unroll
    for (int e = 0; e < 8; ++e) v[e] = W[(size_t)r * 256 + k0 + e];
    u32 hid[4], lod[4];
    #pragma unroll
    for (int p = 0; p < 4; ++p) {
      u16 h0 = f2bf(v[2 * p]), h1 = f2bf(v[2 * p + 1]);
      float l0 = v[2 * p] - bf2f(h0), l1 = v[2 * p + 1] - bf2f(h1);
      hid[p] = (u32)h0 | ((u32)h1 << 16);
      lod[p] = (u32)f2bf(l0) | ((u32)f2bf(l1) << 16);
    }
    size_t hoff = ((((size_t)(layer * 32 + nt) * 16 + kt) * 2 + 0) * 64 + l) * 4;
    size_t loff = hoff + 64 * 4;
    *(uint4*)(wf + hoff) = make_uint4(hid[0], hid[1], hid[2], hid[3]);
    *(uint4*)(wf + loff) = make_uint4(lod[0], lod[1], lod[2], lod[3]);
  } else {
    int t = threadIdx.x;
    for (int i = t; i < 1024; i += 256) flags[i] = 0;
    for (int i = t; i < 256; i += 256) { /* 8 claim areas x 32 u32 */ }
    for (int i = t; i < 256; i += 256) ;
    for (int i = t; i < 256; i += 256)
      claims[i] = ((i & 31) == 16) ? 0xFFFFFFFFu : 0u;
    for (int i = t; i < 1024; i += 256) {
      biasc[i]        = bih0[i] + bhh0[i];
      biasc[1024 + i] = bih1[i] + bhh1[i];
    }
  }
}

// ---------------------------------------------------------------------------
// pack x (B,F,S) -> transposed bf16 hi/lo planes (B,S,F)
// ---------------------------------------------------------------------------
__global__ void k_packx(const float* __restrict__ x,
                        u16* __restrict__ xhi, u16* __restrict__ xlo)
{
  __shared__ float tile[64][65];
  const int s0 = blockIdx.x * 64;
  const int b  = blockIdx.y;
  const int t  = threadIdx.x;
  {
    int ss = t & 63, fq = t >> 6;
    #pragma unroll
    for (int r = 0; r < 16; ++r) {
      int f = fq * 16 + r;
      tile[f][ss] = x[((size_t)b * 64 + f) * 2048 + s0 + ss];
    }
  }
  __syncthreads();
  {
    int f2 = t & 63, sq = t >> 6;
    #pragma unroll
    for (int r = 0; r < 16; ++r) {
      int s = sq * 16 + r;
      float v = tile[f2][s];
      u16 hi = f2bf(v);
      u16 lo = f2bf(v - bf2f(hi));
      size_t o = ((size_t)b * 2048 + s0 + s) * 64 + f2;
      xhi[o] = hi; xlo[o] = lo;
    }
  }
}

// ---------------------------------------------------------------------------
// transpose P1 (B,S,64) f32 -> predT (B,64,S) f32
// ---------------------------------------------------------------------------
__global__ void k_transP(const float* __restrict__ P, float* __restrict__ PT)
{
  __shared__ float tile[64][65];
  const int s0 = blockIdx.x * 64;
  const int b  = blockIdx.y;
  const int t  = threadIdx.x;
  {
    int f = t & 63, sq = t >> 6;
    #pragma unroll
    for (int r = 0; r < 16; ++r) {
      int s = sq * 16 + r;
      tile[s][f] = P[((size_t)b * 2048 + s0 + s) * 64 + f];
    }
  }
  __syncthreads();
  {
    int s2 = t & 63, fq = t >> 6;
    #pragma unroll
    for (int r = 0; r < 16; ++r) {
      int ff = fq * 16 + r;
      PT[((size_t)b * 64 + ff) * 2048 + s0 + s2] = tile[s2][ff];
    }
  }
}

// ---------------------------------------------------------------------------
// generic fp32 TN GEMM (unchanged from R1)
// ---------------------------------------------------------------------------
template<int BM, int BN, int TM, int TN, int MODE, int UA>
__global__ __launch_bounds__(256) void k_gemm(
    const float* __restrict__ Af,
    const u16* __restrict__ Ahi, const u16* __restrict__ Alo,
    const float* __restrict__ Bw,
    const float* __restrict__ bias,
    const float* __restrict__ res,
    float* __restrict__ C,
    int K, int lda,
    long a_zrows, long a_row0, long c_zrows, int ldc)
{
  constexpr int BK = 32;
  __shared__ float As[BK][BM + 4];
  __shared__ float Bs[BK][BN + 4];
  const int t  = threadIdx.x;
  const int tx = t & 15, ty = t >> 4;
  const int mb = blockIdx.x * BM, nb = blockIdx.y * BN;
  const long za = (long)blockIdx.z * a_zrows + a_row0 + mb;
  const long zc = (long)blockIdx.z * c_zrows + mb;

  float acc[TM][TN];
  #pragma unroll
  for (int i = 0; i < TM; ++i)
    #pragma unroll
    for (int jn = 0; jn < TN; ++jn) acc[i][jn] = 0.f;

  for (int k0 = 0; k0 < K; k0 += BK) {
    #pragma unroll
    for (int it = 0; it < BM * 8 / 256; ++it) {
      int idx = it * 256 + t;
      int row = idx >> 3, c4 = idx & 7;
      long ar = za + row;
      float v0, v1, v2, v3;
      if (UA) {
        u64 hh = *(const u64*)(Ahi + (size_t)ar * lda + k0 + c4 * 4);
        u64 ll = *(const u64*)(Alo + (size_t)ar * lda + k0 + c4 * 4);
        v0 = bf2f((u16)hh)         + bf2f((u16)ll);
        v1 = bf2f((u16)(hh >> 16)) + bf2f((u16)(ll >> 16));
        v2 = bf2f((u16)(hh >> 32)) + bf2f((u16)(ll >> 32));
        v3 = bf2f((u16)(hh >> 48)) + bf2f((u16)(ll >> 48));
      } else {
        float4 f4 = *(const float4*)(Af + (size_t)ar * lda + k0 + c4 * 4);
        v0 = f4.x; v1 = f4.y; v2 = f4.z; v3 = f4.w;
      }
      As[c4 * 4 + 0][row] = v0;
      As[c4 * 4 + 1][row] = v1;
      As[c4 * 4 + 2][row] = v2;
      As[c4 * 4 + 3][row] = v3;
    }
    #pragma unroll
    for (int it = 0; it < BN * 8 / 256; ++it) {
      int idx = it * 256 + t;
      int row = idx >> 3, c4 = idx & 7;
      float4 f4 = *(const float4*)(Bw + (size_t)(nb + row) * K + k0 + c4 * 4);
      Bs[c4 * 4 + 0][row] = f4.x;
      Bs[c4 * 4 + 1][row] = f4.y;
      Bs[c4 * 4 + 2][row] = f4.z;
      Bs[c4 * 4 + 3][row] = f4.w;
    }
    __syncthreads();
    #pragma unroll
    for (int kk = 0; kk < BK; ++kk) {
      float av[TM], bv[TN];
      {
        float4 t0 = *(const float4*)&As[kk][ty * TM];
        av[0] = t0.x; av[1] = t0.y; av[2] = t0.z; av[3] = t0.w;
        if (TM == 8) {
          float4 t1 = *(const float4*)&As[kk][ty * TM + 4];
          av[4] = t1.x; av[5] = t1.y; av[6] = t1.z; av[7] = t1.w;
        }
      }
      {
        float4 t0 = *(const float4*)&Bs[kk][tx * TN];
        bv[0] = t0.x; bv[1] = t0.y; bv[2] = t0.z; bv[3] = t0.w;
        if (TN == 8) {
          float4 t1 = *(const float4*)&Bs[kk][tx * TN + 4];
          bv[4] = t1.x; bv[5] = t1.y; bv[6] = t1.z; bv[7] = t1.w;
        }
      }
      #pragma unroll
      for (int i = 0; i < TM; ++i)
        #pragma unroll
        for (int jn = 0; jn < TN; ++jn)
          acc[i][jn] = fmaf(av[i], bv[jn], acc[i][jn]);
    }
    __syncthreads();
  }
  #pragma unroll
  for (int i = 0; i < TM; ++i) {
    long crow = zc + ty * TM + i;
    float* cp = C + (size_t)crow * ldc + nb + tx * TN;
    const float* rp = res + (size_t)crow * ldc + nb + tx * TN;
    #pragma unroll
    for (int jn = 0; jn < TN; ++jn) {
      float v = acc[i][jn] + bias[nb + tx * TN + jn];
      if (MODE == 1) v = silu_f(v);
      else if (MODE == 2) v = rp[jn] + silu_f(v);
      cp[jn] = v;
    }
  }
}

// ---------------------------------------------------------------------------
// XCD-local persistent LSTM scan. 256 wgs launched; 16 self-claim onto one
// XCD (HW_REG_XCC_ID). wg w (4 waves): wave v -> nt = 2w+(v&1), K-half v>>1.
// Per step: sc0 h loads from XCD L2, 24 MFMAs/wave, LDS K-reduce, act waves
// (v<2) do cell update, writethrough h, vmcnt(0), flag, nontemporal hist.
// ---------------------------------------------------------------------------
__global__ __launch_bounds__(256) void k_scan(
    const u32* __restrict__ wf,
    const float* __restrict__ xg,          // [B][cs][1024]
    u16* __restrict__ hbhi, u16* __restrict__ hblo,   // [2][32][256]
    u32* __restrict__ flags,               // 32 flags (per nt), stride 16 u32
    float* __restrict__ cbuf,              // [32][256]
    u16* __restrict__ histhi, u16* __restrict__ histlo, // [B][2048][256]
    u32* __restrict__ claim,               // [32]: cnt[16], winner at [16]
    int t0, int t1, int cs)
{
  __shared__ int s_role;
  if (threadIdx.x == 0) {
    u32 xcc;
    asm volatile("s_getreg_b32 %0, hwreg(20, 0, 4)" : "=s"(xcc));
    xcc &= 15u;
    u32 role = __hip_atomic_fetch_add(&claim[xcc], 1u,
                                      __ATOMIC_RELAXED, __HIP_MEMORY_SCOPE_AGENT);
    if (role == NWG - 1) {
      u32 exp = 0xFFFFFFFFu;
      __hip_atomic_compare_exchange_strong(&claim[16], &exp, xcc,
          __ATOMIC_RELAXED, __ATOMIC_RELAXED, __HIP_MEMORY_SCOPE_AGENT);
    }
    u32 wv; int guard = 0;
    do {
      wv = __hip_atomic_load(&claim[16], __ATOMIC_RELAXED, __HIP_MEMORY_SCOPE_AGENT);
    } while (wv == 0xFFFFFFFFu && ++guard < (1 << 22));
    s_role = (wv == xcc && role < NWG) ? (int)role : -1;
  }
  __syncthreads();
  const int w = s_role;
  if (w < 0) return;

  const int wave = threadIdx.x >> 6;      // 0..3
  const int l    = threadIdx.x & 63;
  const int nt   = 2 * w + (wave & 1);
  const int kh   = wave >> 1;             // K half: kt in [kh*8, kh*8+8)
  const bool act = (wave < 2);

  const int rr  = l & 31;
  const int hi5 = l >> 5;
  const int gate = rr & 3;
  const int jj   = rr >> 2;
  const int q    = l & 3;
  const int j    = nt * 8 + jj;
  const int rorig = gate * 256 + nt * 8 + jj;
  const bool isg = (gate == 2);

  // register-resident weight fragments for this wave's (nt, K-half)
  bf16x8 wh[8], wl[8];
  {
    const u32* p = wf + (size_t)nt * (16 * 2 * 64 * 4);
    #pragma unroll
    for (int kk = 0; kk < 8; ++kk) {
      int kt = kh * 8 + kk;
      union { uint4 u; bf16x8 v; } ua, ub;
      ua.u = *(const uint4*)(p + ((size_t)(kt * 2 + 0) * 64 + l) * 4);
      ub.u = *(const uint4*)(p + ((size_t)(kt * 2 + 1) * 64 + l) * 4);
      wh[kk] = ua.v; wl[kk] = ub.v;
    }
  }

  float c4v[4] = {0.f, 0.f, 0.f, 0.f};
  if (act && t0 > 0) {
    #pragma unroll
    for (int ri = 0; ri < 4; ++ri)
      c4v[ri] = cbuf[(size_t)(8 * q + 4 * hi5 + ri) * 256 + j];
  }

  __shared__ __align__(16) float racc[2][64][16];     // K-partner partials
  __shared__ __align__(16) float zex[2][2][16][36];   // per act wave

  for (int t = t0; t < t1; ++t) {
    // xg loads for this step (nontemporal; issued before the poll)
    float xgv[16];
    if (act) {
      #pragma unroll
      for (int reg = 0; reg < 16; ++reg) {
        int b = (reg & 3) + 8 * (reg >> 2) + 4 * hi5;
        xgv[reg] = __builtin_nontemporal_load(
            xg + ((size_t)b * cs + (t - t0)) * 1024 + rorig);
      }
    }

    f32x16 aA = {}, aB = {}, aC = {};
    if (t > 0) {
      {   // poll all 32 nt flags through the XCD L2
        const u32 tgt = (u32)t;
        const u32* fp = flags + (size_t)(l & 31) * 16;
        int guard = 0;
        while (true) {
          u32 fv = poll_load_u32(fp);
          if (__all((int)(fv >= tgt))) break;
          if (++guard > (1 << 14)) break;   // bail, never hang
        }
      }
      const u16* bh = hbhi + (size_t)(t & 1) * (32 * 256);
      const u16* bl = hblo + (size_t)(t & 1) * (32 * 256);
      const size_t abase = (size_t)(l & 31) * 256 + (size_t)hi5 * 8;
      u64 H0[8], H1[8], G0[8], G1[8];
      #pragma unroll
      for (int kk = 0; kk < 8; ++kk) {
        size_t o = abase + (size_t)(kh * 8 + kk) * 16;
        H0[kk] = load_sc0_u64(bh + o);
        H1[kk] = load_sc0_u64(bh + o + 4);
        G0[kk] = load_sc0_u64(bl + o);
        G1[kk] = load_sc0_u64(bl + o + 4);
      }
      asm volatile("s_waitcnt vmcnt(0)" ::: "memory");
      __builtin_amdgcn_sched_barrier(0);
      #pragma unroll
      for (int kk = 0; kk < 8; ++kk) {
        bf16x8 ah = mk8(H0[kk], H1[kk]);
        bf16x8 al = mk8(G0[kk], G1[kk]);
        aA = __builtin_amdgcn_mfma_f32_32x32x16_bf16(ah, wh[kk], aA, 0, 0, 0);
        aB = __builtin_amdgcn_mfma_f32_32x32x16_bf16(al, wh[kk], aB, 0, 0, 0);
        aC = __builtin_amdgcn_mfma_f32_32x32x16_bf16(ah, wl[kk], aC, 0, 0, 0);
      }
    }
    f32x16 accsum = (aA + aB) + aC;

    if (!act) {
      #pragma unroll
      for (int i = 0; i < 16; ++i) racc[wave - 2][l][i] = accsum[i];
    }
    __syncthreads();   // single barrier per step (flag-poll orders the rest)

    if (act) {
      #pragma unroll
      for (int reg = 0; reg < 16; ++reg) {
        float pre = accsum[reg] + racc[wave][l][reg] + xgv[reg];
        float s = isg ? (2.f * pre) : pre;
        float y = sig_fast(s);
        zex[wave][hi5][reg][rr] = isg ? (2.f * y - 1.f) : y;
      }
      // zex written/read by the same wave only — no barrier needed
      u16* dh = hbhi + (size_t)((t + 1) & 1) * (32 * 256);
      u16* dl = hblo + (size_t)((t + 1) & 1) * (32 * 256);
      u16 shv[4], slv[4];
      #pragma unroll
      for (int ri = 0; ri < 4; ++ri) {
        const float4 gv = *(const float4*)&zex[wave][hi5][q * 4 + ri][jj * 4];
        float cn = fmaf(gv.y, c4v[ri], gv.x * gv.z);
        c4v[ri] = cn;
        float th = 2.f * sig_fast(2.f * cn) - 1.f;
        float hv = gv.w * th;
        u16 sh = f2bf(hv);
        u16 sl = f2bf(hv - bf2f(sh));
        shv[ri] = sh; slv[ri] = sl;
        int b = 8 * q + 4 * hi5 + ri;
        dh[(size_t)b * 256 + j] = sh;   // plain writethrough -> XCD L2
        dl[(size_t)b * 256 + j] = sl;
      }
      asm volatile("s_waitcnt vmcnt(0)" ::: "memory");   // h visible in L2
      *(volatile u32*)(flags + (size_t)nt * 16) = (u32)(t + 1);
      #pragma unroll
      for (int ri = 0; ri < 4; ++ri) {   // hist off the critical path
        int b = 8 * q + 4 * hi5 + ri;
        size_t ho = ((size_t)b * 2048 + t) * 256 + j;
        __builtin_nontemporal_store(shv[ri], histhi + ho);
        __builtin_nontemporal_store(slv[ri], histlo + ho);
      }
    }
  }
  if (act) {
    #pragma unroll
    for (int ri = 0; ri < 4; ++ri)
      cbuf[(size_t)(8 * q + 4 * hi5 + ri) * 256 + j] = c4v[ri];
  }
}

// ---------------------------------------------------------------------------
// softmax over rows of 2048
// ---------------------------------------------------------------------------
__global__ __launch_bounds__(256) void k_softmax(const float* __restrict__ X,
                                                 float* __restrict__ O)
{
  __shared__ float red[256];
  const int t = threadIdx.x;
  const size_t row = blockIdx.x;
  const float* xr = X + row * 2048;
  float v[8];
  {
    float4 va = *(const float4*)(xr + t * 8);
    float4 vb = *(const float4*)(xr + t * 8 + 4);
    v[0]=va.x; v[1]=va.y; v[2]=va.z; v[3]=va.w;
    v[4]=vb.x; v[5]=vb.y; v[6]=vb.z; v[7]=vb.w;
  }
  float m = v[0];
  #pragma unroll
  for (int i = 1; i < 8; ++i) m = fmaxf(m, v[i]);
  red[t] = m; __syncthreads();
  for (int s = 128; s > 0; s >>= 1) {
    if (t < s) red[t] = fmaxf(red[t], red[t + s]);
    __syncthreads();
  }
  m = red[0];
  __syncthreads();
  float sum = 0.f;
  #pragma unroll
  for (int i = 0; i < 8; ++i) { v[i] = __expf(v[i] - m); sum += v[i]; }
  red[t] = sum; __syncthreads();
  for (int s = 128; s > 0; s >>= 1) {
    if (t < s) red[t] += red[t + s];
    __syncthreads();
  }
  const float inv = 1.f / red[0];
  float* op = O + row * 2048 + t * 8;
  float4 oa = { v[0]*inv, v[1]*inv, v[2]*inv, v[3]*inv };
  float4 ob = { v[4]*inv, v[5]*inv, v[6]*inv, v[7]*inv };
  *(float4*)op = oa;
  *(float4*)(op + 4) = ob;
}

// ---------------------------------------------------------------------------
extern "C" void kernel_launch(void* const* d_in, const int* in_sizes, int n_in,
                              void* d_out, int out_size, void* d_ws, size_t ws_size,
                              hipStream_t stream)
{
  const float* x    = (const float*)d_in[0];
  const float* Wih0 = (const float*)d_in[1];
  const float* Whh0 = (const float*)d_in[2];
  const float* bih0 = (const float*)d_in[3];
  const float* bhh0 = (const float*)d_in[4];
  const float* Wih1 = (const float*)d_in[5];
  const float* Whh1 = (const float*)d_in[6];
  const float* bih1 = (const float*)d_in[7];
  const float* bhh1 = (const float*)d_in[8];
  const float* W1   = (const float*)d_in[9];
  const float* b1   = (const float*)d_in[10];
  const float* W1b  = (const float*)d_in[11];
  const float* b1b  = (const float*)d_in[12];
  const float* W2   = (const float*)d_in[13];
  const float* b2   = (const float*)d_in[14];
  const float* W2b  = (const float*)d_in[15];
  const float* b2b  = (const float*)d_in[16];
  (void)in_sizes; (void)n_in;

  const size_t PL = (size_t)32 * 2048 * 256 * 2;
  const size_t XT = (size_t)32 * 2048 * 64 * 2;
  const size_t WF = (size_t)2 * 32 * 16 * 2 * 64 * 16;

  auto need = [&](int c) -> size_t {
    return (size_t)32 * c * 1024 * 4 + 4 * PL + 2 * XT + WF + (1u << 20);
  };
  int cs = 1024;
  while (cs > 128 && need(cs) > ws_size) cs >>= 1;
  if (need(cs) > ws_size) {
    hipMemsetAsync(d_out, 0x7F, (size_t)out_size * 4, stream);
    return;
  }

  char* w = (char*)d_ws;
  size_t off = 0;
  auto take = [&](size_t bytes) {
    size_t r = off;
    off = (off + bytes + 255) & ~(size_t)255;
    return r;
  };
  size_t o_xg   = take((size_t)32 * cs * 1024 * 4);
  size_t o_h0hi = take(PL), o_h0lo = take(PL);
  size_t o_h1hi = take(PL), o_h1lo = take(PL);
  size_t o_xthi = take(XT), o_xtlo = take(XT);
  size_t o_wf   = take(WF);
  size_t o_bias = take(8192);
  size_t o_hbhi = take(2 * 32 * 256 * 2);
  size_t o_hblo = take(2 * 32 * 256 * 2);
  size_t o_flag = take(4096);
  size_t o_cbuf = take(32 * 256 * 4);
  size_t o_clm  = take(8 * 32 * 4);

  float* xg    = (float*)(w + o_xg);
  u16*   h0hi  = (u16*)(w + o_h0hi);
  u16*   h0lo  = (u16*)(w + o_h0lo);
  u16*   h1hi  = (u16*)(w + o_h1hi);
  u16*   h1lo  = (u16*)(w + o_h1lo);
  u16*   xthi  = (u16*)(w + o_xthi);
  u16*   xtlo  = (u16*)(w + o_xtlo);
  u32*   wf    = (u32*)(w + o_wf);
  float* biasc = (float*)(w + o_bias);
  u16*   hbhi  = (u16*)(w + o_hbhi);
  u16*   hblo  = (u16*)(w + o_hblo);
  u32*   flags = (u32*)(w + o_flag);
  float* cbuf  = (float*)(w + o_cbuf);
  u32*   clms  = (u32*)(w + o_clm);
  float* P0    = (float*)(w + o_h0hi);
  float* P1    = (float*)(w + o_h0hi + 16777216);
  float* predT = (float*)(w + o_h0lo);
  float* out1  = (float*)(w + o_h0lo + 16777216);
  float* out2  = (float*)(w + o_h1hi);

  k_prep<<<257, 256, 0, stream>>>(Whh0, Whh1, bih0, bhh0, bih1, bhh1,
                                  wf, biasc, flags, clms);
  k_packx<<<dim3(32, 32), 256, 0, stream>>>(x, xthi, xtlo);

  const int Q = 2048 / cs;
  int li = 0;
  for (int qq = 0; qq < Q; ++qq) {
    k_gemm<128, 128, 8, 8, 0, 1><<<dim3(cs / 128, 8, 32), 256, 0, stream>>>(
        nullptr, xthi, xtlo, Wih0, biasc, xg, xg,
        64, 64, 2048, (long)qq * cs, cs, 1024);
    k_scan<<<256, 256, 0, stream>>>(wf, xg, hbhi, hblo, flags, cbuf,
                                    h0hi, h0lo, clms + (li++) * 32,
                                    qq * cs, (qq + 1) * cs, cs);
  }
  for (int qq = 0; qq < Q; ++qq) {
    k_gemm<128, 128, 8, 8, 0, 1><<<dim3(cs / 128, 8, 32), 256, 0, stream>>>(
        nullptr, h0hi, h0lo, Wih1, biasc + 1024, xg, xg,
        256, 256, 2048, (long)qq * cs, cs, 1024);
    k_scan<<<256, 256, 0, stream>>>(wf + (size_t)32 * 16 * 2 * 64 * 4, xg,
                                    hbhi, hblo, flags + 512, cbuf,
                                    h1hi, h1lo, clms + (li++) * 32,
                                    qq * cs, (qq + 1) * cs, cs);
  }
  // heads
  k_gemm<128, 64, 8, 4, 1, 1><<<dim3(512, 1, 1), 256, 0, stream>>>(
      nullptr, h1hi, h1lo, W1, b1, P0, P0, 256, 256, 0, 0, 0, 64);
  k_gemm<128, 64, 8, 4, 2, 0><<<dim3(512, 1, 1), 256, 0, stream>>>(
      P0, nullptr, nullptr, W1b, b1b, P0, P1, 64, 64, 0, 0, 0, 64);
  k_transP<<<dim3(32, 32), 256, 0, stream>>>(P1, predT);
  k_gemm<128, 128, 8, 8, 0, 0><<<dim3(16, 16, 1), 256, 0, stream>>>(
      predT, nullptr, nullptr, W2, b2, out1, out1, 2048, 2048, 0, 0, 0, 2048);
  k_gemm<128, 128, 8, 8, 2, 0><<<dim3(16, 16, 1), 256, 0, stream>>>(
      out1, nullptr, nullptr, W2b, b2b, out1, out2, 2048, 2048, 0, 0, 0, 2048);
  k_softmax<<<2048, 256, 0, stream>>>(out2, (float*)d_out);
}

// Round 3
// 46817.868 us; speedup vs baseline: 153.6023x; 153.6023x over previous
//
// LSTM_45337674776685 — R3: tag-in-data h exchange through the XCD L2.
// R2 post-mortem: sc0 loads are NOT an L1 bypass (agent scope is sc1) -> polls
// spun on stale L1 lines until guard-bail (235x slowdown). R3: all poll/data
// reads use `nt` (no L1 allocate -> re-probe L2 each retry) with sc1
// escalation; h published as (hi16|lo14|tag2) u32 so data+tag are atomically
// visible and completion races are detected by tag-retry, never trusted.
// Producer: 4 sc1 stores + sc1 flag, fire-and-forget (no vmcnt). 16wgs x
// 4waves self-claimed onto one XCD; weights register-resident bf16 hi/lo;
// 3x mfma_f32_32x32x16_bf16 per k-tile (emulated fp32).

#include <hip/hip_runtime.h>
#include <stdint.h>

typedef unsigned short u16;
typedef unsigned int   u32;
typedef unsigned long long u64;

typedef short  bf16x8 __attribute__((ext_vector_type(8)));
typedef float  f32x16 __attribute__((ext_vector_type(16)));

#define DEVI static __device__ __forceinline__
#define NWG 16

DEVI u16 f2bf(float x) {
  u32 u = __float_as_uint(x);
  u += 0x7FFFu + ((u >> 16) & 1u);
  return (u16)(u >> 16);
}
DEVI float bf2f(u16 h) { return __uint_as_float(((u32)h) << 16); }

DEVI float sig_fast(float x) {
  float d = 1.f + __expf(-x);
  float r = __builtin_amdgcn_rcpf(d);
  return r * (2.f - d * r);
}
DEVI float silu_f(float x) { return x * sig_fast(x); }

// nt loads: no L1 allocate -> every retry re-probes the XCD L2.
// sc1 loads/stores: agent scope (MALL) -- the always-correct escalation path.
DEVI u32 ld32_nt(const u32* p) {
  u32 v;
  asm volatile("global_load_dword %0, %1, off nt\n\ts_waitcnt vmcnt(0)"
               : "=v"(v) : "v"(p) : "memory");
  return v;
}
DEVI u32 ld32_sc1(const u32* p) {
  u32 v;
  asm volatile("global_load_dword %0, %1, off sc1\n\ts_waitcnt vmcnt(0)"
               : "=v"(v) : "v"(p) : "memory");
  return v;
}
DEVI u64 ld64_nt(const u32* p) {
  u64 v;
  asm volatile("global_load_dwordx2 %0, %1, off nt" : "=v"(v) : "v"(p) : "memory");
  return v;
}
DEVI u64 ld64_sc1(const u32* p) {
  u64 v;
  asm volatile("global_load_dwordx2 %0, %1, off sc1" : "=v"(v) : "v"(p) : "memory");
  return v;
}
DEVI void st32_sc1(u32* p, u32 v) {
  asm volatile("global_store_dword %0, %1, off sc1" :: "v"(p), "v"(v) : "memory");
}

// ---------------------------------------------------------------------------
// prep: pack W_hh0/1 into MFMA B-fragments (blocks 0-255), init hp tags
// (blocks 256-511), flags/bias/claims (block 512). Runs EVERY launch so
// replays never see stale flags/tags.
// ---------------------------------------------------------------------------
__global__ void k_prep(const float* __restrict__ Whh0, const float* __restrict__ Whh1,
                       const float* __restrict__ bih0, const float* __restrict__ bhh0,
                       const float* __restrict__ bih1, const float* __restrict__ bhh1,
                       u32* __restrict__ wf, float* __restrict__ biasc,
                       u32* __restrict__ hp, u32* __restrict__ flg,
                       u32* __restrict__ claims)
{
  if (blockIdx.x < 256) {
    int g = blockIdx.x * 256 + threadIdx.x;
    int layer = g >> 15;
    int nt = (g >> 10) & 31;
    int kt = (g >> 6) & 15;
    int l  = g & 63;
    int rr = l & 31, gate = rr & 3, jj = rr >> 2;
    int r  = gate * 256 + nt * 8 + jj;
    int k0 = kt * 16 + (l >> 5) * 8;
    const float* W = layer ? Whh1 : Whh0;
    float v[8];
    #pragma unroll
    for (int e = 0; e < 8; ++e) v[e] = W[(size_t)r * 256 + k0 + e];
    u32 hid[4], lod[4];
    #pragma unroll
    for (int p = 0; p < 4; ++p) {
      u16 h0 = f2bf(v[2 * p]), h1 = f2bf(v[2 * p + 1]);
      float l0 = v[2 * p] - bf2f(h0), l1 = v[2 * p + 1] - bf2f(h1);
      hid[p] = (u32)h0 | ((u32)h1 << 16);
      lod[p] = (u32)f2bf(l0) | ((u32)f2bf(l1) << 16);
    }
    size_t hoff = ((((size_t)(layer * 32 + nt) * 16 + kt) * 2 + 0) * 64 + l) * 4;
    size_t loff = hoff + 64 * 4;
    *(uint4*)(wf + hoff) = make_uint4(hid[0], hid[1], hid[2], hid[3]);
    *(uint4*)(wf + loff) = make_uint4(lod[0], lod[1], lod[2], lod[3]);
  } else if (blockIdx.x < 512) {
    // hp init: 2 layers x 4 bufs x 32 x 256 = 65536 u32, tag bits = 2
    int idx = (blockIdx.x - 256) * 256 + threadIdx.x;
    hp[idx] = 2u;
  } else {
    int t = threadIdx.x;
    for (int i = t; i < 1024; i += 256) flg[i] = 0;           // 2 layers x 512
    claims[t] = ((t & 31) == 16) ? 0xFFFFFFFFu : 0u;          // 8 areas x 32
    for (int i = t; i < 1024; i += 256) {
      biasc[i]        = bih0[i] + bhh0[i];
      biasc[1024 + i] = bih1[i] + bhh1[i];
    }
  }
}

// ---------------------------------------------------------------------------
// pack x (B,F,S) -> transposed packed u32 (B,S,F): (hi<<16)|lo
// ---------------------------------------------------------------------------
__global__ void k_packx(const float* __restrict__ x, u32* __restrict__ xp)
{
  __shared__ float tile[64][65];
  const int s0 = blockIdx.x * 64;
  const int b  = blockIdx.y;
  const int t  = threadIdx.x;
  {
    int ss = t & 63, fq = t >> 6;
    #pragma unroll
    for (int r = 0; r < 16; ++r) {
      int f = fq * 16 + r;
      tile[f][ss] = x[((size_t)b * 64 + f) * 2048 + s0 + ss];
    }
  }
  __syncthreads();
  {
    int f2 = t & 63, sq = t >> 6;
    #pragma unroll
    for (int r = 0; r < 16; ++r) {
      int s = sq * 16 + r;
      float v = tile[f2][s];
      u16 hi = f2bf(v);
      u16 lo = f2bf(v - bf2f(hi));
      xp[((size_t)b * 2048 + s0 + s) * 64 + f2] = ((u32)hi << 16) | lo;
    }
  }
}

// ---------------------------------------------------------------------------
// transpose P1 (B,S,64) f32 -> predT (B,64,S) f32
// ---------------------------------------------------------------------------
__global__ void k_transP(const float* __restrict__ P, float* __restrict__ PT)
{
  __shared__ float tile[64][65];
  const int s0 = blockIdx.x * 64;
  const int b  = blockIdx.y;
  const int t  = threadIdx.x;
  {
    int f = t & 63, sq = t >> 6;
    #pragma unroll
    for (int r = 0; r < 16; ++r) {
      int s = sq * 16 + r;
      tile[s][f] = P[((size_t)b * 2048 + s0 + s) * 64 + f];
    }
  }
  __syncthreads();
  {
    int s2 = t & 63, fq = t >> 6;
    #pragma unroll
    for (int r = 0; r < 16; ++r) {
      int ff = fq * 16 + r;
      PT[((size_t)b * 64 + ff) * 2048 + s0 + s2] = tile[s2][ff];
    }
  }
}

// ---------------------------------------------------------------------------
// generic fp32 TN GEMM. UA: A is packed u32 (hi<<16|lo), value = hi + lo.
// MODE 0: +bias ; 1: silu(+bias) ; 2: res + silu(+bias)
// ---------------------------------------------------------------------------
template<int BM, int BN, int TM, int TN, int MODE, int UA>
__global__ __launch_bounds__(256) void k_gemm(
    const float* __restrict__ Af,
    const u32* __restrict__ Ap,
    const float* __restrict__ Bw,
    const float* __restrict__ bias,
    const float* __restrict__ res,
    float* __restrict__ C,
    int K, int lda,
    long a_zrows, long a_row0, long c_zrows, int ldc)
{
  constexpr int BK = 32;
  __shared__ float As[BK][BM + 4];
  __shared__ float Bs[BK][BN + 4];
  const int t  = threadIdx.x;
  const int tx = t & 15, ty = t >> 4;
  const int mb = blockIdx.x * BM, nb = blockIdx.y * BN;
  const long za = (long)blockIdx.z * a_zrows + a_row0 + mb;
  const long zc = (long)blockIdx.z * c_zrows + mb;

  float acc[TM][TN];
  #pragma unroll
  for (int i = 0; i < TM; ++i)
    #pragma unroll
    for (int jn = 0; jn < TN; ++jn) acc[i][jn] = 0.f;

  for (int k0 = 0; k0 < K; k0 += BK) {
    #pragma unroll
    for (int it = 0; it < BM * 8 / 256; ++it) {
      int idx = it * 256 + t;
      int row = idx >> 3, c4 = idx & 7;
      long ar = za + row;
      float v0, v1, v2, v3;
      if (UA) {
        uint4 qv = *(const uint4*)(Ap + (size_t)ar * lda + k0 + c4 * 4);
        v0 = bf2f((u16)(qv.x >> 16)) + bf2f((u16)(qv.x & 0xFFFFu));
        v1 = bf2f((u16)(qv.y >> 16)) + bf2f((u16)(qv.y & 0xFFFFu));
        v2 = bf2f((u16)(qv.z >> 16)) + bf2f((u16)(qv.z & 0xFFFFu));
        v3 = bf2f((u16)(qv.w >> 16)) + bf2f((u16)(qv.w & 0xFFFFu));
      } else {
        float4 f4 = *(const float4*)(Af + (size_t)ar * lda + k0 + c4 * 4);
        v0 = f4.x; v1 = f4.y; v2 = f4.z; v3 = f4.w;
      }
      As[c4 * 4 + 0][row] = v0;
      As[c4 * 4 + 1][row] = v1;
      As[c4 * 4 + 2][row] = v2;
      As[c4 * 4 + 3][row] = v3;
    }
    #pragma unroll
    for (int it = 0; it < BN * 8 / 256; ++it) {
      int idx = it * 256 + t;
      int row = idx >> 3, c4 = idx & 7;
      float4 f4 = *(const float4*)(Bw + (size_t)(nb + row) * K + k0 + c4 * 4);
      Bs[c4 * 4 + 0][row] = f4.x;
      Bs[c4 * 4 + 1][row] = f4.y;
      Bs[c4 * 4 + 2][row] = f4.z;
      Bs[c4 * 4 + 3][row] = f4.w;
    }
    __syncthreads();
    #pragma unroll
    for (int kk = 0; kk < BK; ++kk) {
      float av[TM], bv[TN];
      {
        float4 t0 = *(const float4*)&As[kk][ty * TM];
        av[0] = t0.x; av[1] = t0.y; av[2] = t0.z; av[3] = t0.w;
        if (TM == 8) {
          float4 t1 = *(const float4*)&As[kk][ty * TM + 4];
          av[4] = t1.x; av[5] = t1.y; av[6] = t1.z; av[7] = t1.w;
        }
      }
      {
        float4 t0 = *(const float4*)&Bs[kk][tx * TN];
        bv[0] = t0.x; bv[1] = t0.y; bv[2] = t0.z; bv[3] = t0.w;
        if (TN == 8) {
          float4 t1 = *(const float4*)&Bs[kk][tx * TN + 4];
          bv[4] = t1.x; bv[5] = t1.y; bv[6] = t1.z; bv[7] = t1.w;
        }
      }
      #pragma unroll
      for (int i = 0; i < TM; ++i)
        #pragma unroll
        for (int jn = 0; jn < TN; ++jn)
          acc[i][jn] = fmaf(av[i], bv[jn], acc[i][jn]);
    }
    __syncthreads();
  }
  #pragma unroll
  for (int i = 0; i < TM; ++i) {
    long crow = zc + ty * TM + i;
    float* cp = C + (size_t)crow * ldc + nb + tx * TN;
    const float* rp = res + (size_t)crow * ldc + nb + tx * TN;
    #pragma unroll
    for (int jn = 0; jn < TN; ++jn) {
      float v = acc[i][jn] + bias[nb + tx * TN + jn];
      if (MODE == 1) v = silu_f(v);
      else if (MODE == 2) v = rp[jn] + silu_f(v);
      cp[jn] = v;
    }
  }
}

// ---------------------------------------------------------------------------
// persistent LSTM scan, XCD-claimed. hp[4][32][256] u32 = (hi16|lo14|tag2),
// flg[16][32] rotating flags. Consumers: nt poll + nt data + tag verify,
// sc1 escalation. Producers: sc1 stores, no vmcnt on critical path.
// ---------------------------------------------------------------------------
__global__ __launch_bounds__(256) void k_scan(
    const u32* __restrict__ wf,
    const float* __restrict__ xg,          // [B][cs][1024]
    u32* __restrict__ hp,                  // [4][32][256]
    u32* __restrict__ flg,                 // [16][32]
    float* __restrict__ cbuf,              // [32][256]
    u32* __restrict__ histp,               // [B][2048][256]
    u32* __restrict__ claim,               // [32]
    int t0, int t1, int cs)
{
  __shared__ int s_role;
  if (threadIdx.x == 0) {
    u32 xcc;
    asm volatile("s_getreg_b32 %0, hwreg(20, 0, 4)" : "=s"(xcc));
    xcc &= 15u;
    u32 role = __hip_atomic_fetch_add(&claim[xcc], 1u,
                                      __ATOMIC_RELAXED, __HIP_MEMORY_SCOPE_AGENT);
    if (role == NWG - 1) {
      u32 exp = 0xFFFFFFFFu;
      __hip_atomic_compare_exchange_strong(&claim[16], &exp, xcc,
          __ATOMIC_RELAXED, __ATOMIC_RELAXED, __HIP_MEMORY_SCOPE_AGENT);
    }
    u32 wv; int guard = 0;
    do {
      wv = __hip_atomic_load(&claim[16], __ATOMIC_RELAXED, __HIP_MEMORY_SCOPE_AGENT);
    } while (wv == 0xFFFFFFFFu && ++guard < (1 << 17));
    s_role = (wv == xcc && role < NWG) ? (int)role : -1;
  }
  __syncthreads();
  const int w = s_role;
  if (w < 0) return;

  const int wave = threadIdx.x >> 6;      // 0..3
  const int l    = threadIdx.x & 63;
  const int nt   = 2 * w + (wave & 1);
  const int kh   = wave >> 1;             // K half
  const bool act = (wave < 2);

  const int rr  = l & 31;
  const int hi5 = l >> 5;
  const int gate = rr & 3;
  const int jj   = rr >> 2;
  const int q    = l & 3;
  const int j    = nt * 8 + jj;
  const int rorig = gate * 256 + nt * 8 + jj;
  const bool isg = (gate == 2);

  bf16x8 wh[8], wl[8];
  {
    const u32* p = wf + (size_t)nt * (16 * 2 * 64 * 4);
    #pragma unroll
    for (int kk = 0; kk < 8; ++kk) {
      int kt = kh * 8 + kk;
      union { uint4 u; bf16x8 v; } ua, ub;
      ua.u = *(const uint4*)(p + ((size_t)(kt * 2 + 0) * 64 + l) * 4);
      ub.u = *(const uint4*)(p + ((size_t)(kt * 2 + 1) * 64 + l) * 4);
      wh[kk] = ua.v; wl[kk] = ub.v;
    }
  }

  float c4v[4] = {0.f, 0.f, 0.f, 0.f};
  if (act && t0 > 0) {
    #pragma unroll
    for (int ri = 0; ri < 4; ++ri)
      c4v[ri] = cbuf[(size_t)(8 * q + 4 * hi5 + ri) * 256 + j];
  }

  __shared__ __align__(16) float racc[2][64][16];
  __shared__ __align__(16) float zex[2][2][16][36];

  for (int t = t0; t < t1; ++t) {
    float xgv[16];
    if (act) {
      #pragma unroll
      for (int reg = 0; reg < 16; ++reg) {
        int b = (reg & 3) + 8 * (reg >> 2) + 4 * hi5;
        xgv[reg] = __builtin_nontemporal_load(
            xg + ((size_t)b * cs + (t - t0)) * 1024 + rorig);
      }
    }

    f32x16 aA = {}, aB = {}, aC = {};
    if (t > 0) {
      const u32 et = ((u32)t >> 2) & 3u;
      {   // poll the 16 producer flags of this wave's K-half
        const u32* fp = flg + ((u32)t & 15u) * 32 + kh * 16 + (l & 15);
        int att = 0;
        while (true) {
          u32 fv = (att < 64) ? ld32_nt(fp) : ld32_sc1(fp);
          if (__all((int)(fv >= (u32)t))) break;
          if (++att > (1 << 13)) break;
        }
      }
      const u32* hpb = hp + ((u32)t & 3u) * 8192 + (u32)(l & 31) * 256
                         + kh * 128 + hi5 * 8;
      u64 d[32];
      int datt = 0;
      while (true) {
        if (datt < 8) {
          #pragma unroll
          for (int kk = 0; kk < 8; ++kk) {
            const u32* p = hpb + kk * 16;
            d[kk*4+0] = ld64_nt(p);     d[kk*4+1] = ld64_nt(p + 2);
            d[kk*4+2] = ld64_nt(p + 4); d[kk*4+3] = ld64_nt(p + 6);
          }
        } else {
          #pragma unroll
          for (int kk = 0; kk < 8; ++kk) {
            const u32* p = hpb + kk * 16;
            d[kk*4+0] = ld64_sc1(p);     d[kk*4+1] = ld64_sc1(p + 2);
            d[kk*4+2] = ld64_sc1(p + 4); d[kk*4+3] = ld64_sc1(p + 6);
          }
        }
        asm volatile("s_waitcnt vmcnt(0)" ::: "memory");
        u32 orv = 0;
        #pragma unroll
        for (int i = 0; i < 32; ++i) {
          u32 a = (u32)d[i], b = (u32)(d[i] >> 32);
          orv |= (a ^ et) | (b ^ et);
        }
        if (__all((int)((orv & 3u) == 0u))) break;
        if (++datt > (1 << 10)) break;
      }
      #pragma unroll
      for (int kk = 0; kk < 8; ++kk) {
        u32 e[8];
        #pragma unroll
        for (int m = 0; m < 4; ++m) {
          e[2*m]   = (u32)d[kk*4+m];
          e[2*m+1] = (u32)(d[kk*4+m] >> 32);
        }
        union { uint4 u; bf16x8 v; } ua, ub;
        ua.u = make_uint4(__builtin_amdgcn_perm(e[1], e[0], 0x07060302u),
                          __builtin_amdgcn_perm(e[3], e[2], 0x07060302u),
                          __builtin_amdgcn_perm(e[5], e[4], 0x07060302u),
                          __builtin_amdgcn_perm(e[7], e[6], 0x07060302u));
        ub.u = make_uint4(__builtin_amdgcn_perm(e[1], e[0], 0x05040100u) & 0xFFFCFFFCu,
                          __builtin_amdgcn_perm(e[3], e[2], 0x05040100u) & 0xFFFCFFFCu,
                          __builtin_amdgcn_perm(e[5], e[4], 0x05040100u) & 0xFFFCFFFCu,
                          __builtin_amdgcn_perm(e[7], e[6], 0x05040100u) & 0xFFFCFFFCu);
        aA = __builtin_amdgcn_mfma_f32_32x32x16_bf16(ua.v, wh[kk], aA, 0, 0, 0);
        aB = __builtin_amdgcn_mfma_f32_32x32x16_bf16(ub.v, wh[kk], aB, 0, 0, 0);
        aC = __builtin_amdgcn_mfma_f32_32x32x16_bf16(ua.v, wl[kk], aC, 0, 0, 0);
      }
    }
    f32x16 accsum = (aA + aB) + aC;

    if (!act) {
      #pragma unroll
      for (int i = 0; i < 16; ++i) racc[wave - 2][l][i] = accsum[i];
    }
    __syncthreads();

    if (act) {
      #pragma unroll
      for (int reg = 0; reg < 16; ++reg) {
        float pre = accsum[reg] + racc[wave][l][reg] + xgv[reg];
        float s = isg ? (2.f * pre) : pre;
        float y = sig_fast(s);
        zex[wave][hi5][reg][rr] = isg ? (2.f * y - 1.f) : y;
      }
      const u32 nb3 = ((u32)(t + 1)) & 3u;
      const u32 tg  = (((u32)(t + 1)) >> 2) & 3u;
      u32* dst = hp + nb3 * 8192;
      u32 hk[4];
      #pragma unroll
      for (int ri = 0; ri < 4; ++ri) {
        const float4 gv = *(const float4*)&zex[wave][hi5][q * 4 + ri][jj * 4];
        float cn = fmaf(gv.y, c4v[ri], gv.x * gv.z);
        c4v[ri] = cn;
        float th = 2.f * sig_fast(2.f * cn) - 1.f;
        float hv = gv.w * th;
        u16 sh = f2bf(hv);
        u16 sl = f2bf(hv - bf2f(sh));
        int b = 8 * q + 4 * hi5 + ri;
        st32_sc1(dst + (size_t)b * 256 + j,
                 ((u32)sh << 16) | ((u32)sl & 0xFFFCu) | tg);
        hk[ri] = ((u32)sh << 16) | (u32)sl;
      }
      st32_sc1(flg + (((u32)(t + 1)) & 15u) * 32 + nt, (u32)(t + 1));
      #pragma unroll
      for (int ri = 0; ri < 4; ++ri) {
        int b = 8 * q + 4 * hi5 + ri;
        __builtin_nontemporal_store(hk[ri], histp + ((size_t)b * 2048 + t) * 256 + j);
      }
    }
  }
  if (act) {
    #pragma unroll
    for (int ri = 0; ri < 4; ++ri)
      cbuf[(size_t)(8 * q + 4 * hi5 + ri) * 256 + j] = c4v[ri];
  }
}

// ---------------------------------------------------------------------------
// softmax over rows of 2048
// ---------------------------------------------------------------------------
__global__ __launch_bounds__(256) void k_softmax(const float* __restrict__ X,
                                                 float* __restrict__ O)
{
  __shared__ float red[256];
  const int t = threadIdx.x;
  const size_t row = blockIdx.x;
  const float* xr = X + row * 2048;
  float v[8];
  {
    float4 va = *(const float4*)(xr + t * 8);
    float4 vb = *(const float4*)(xr + t * 8 + 4);
    v[0]=va.x; v[1]=va.y; v[2]=va.z; v[3]=va.w;
    v[4]=vb.x; v[5]=vb.y; v[6]=vb.z; v[7]=vb.w;
  }
  float m = v[0];
  #pragma unroll
  for (int i = 1; i < 8; ++i) m = fmaxf(m, v[i]);
  red[t] = m; __syncthreads();
  for (int s = 128; s > 0; s >>= 1) {
    if (t < s) red[t] = fmaxf(red[t], red[t + s]);
    __syncthreads();
  }
  m = red[0];
  __syncthreads();
  float sum = 0.f;
  #pragma unroll
  for (int i = 0; i < 8; ++i) { v[i] = __expf(v[i] - m); sum += v[i]; }
  red[t] = sum; __syncthreads();
  for (int s = 128; s > 0; s >>= 1) {
    if (t < s) red[t] += red[t + s];
    __syncthreads();
  }
  const float inv = 1.f / red[0];
  float* op = O + row * 2048 + t * 8;
  float4 oa = { v[0]*inv, v[1]*inv, v[2]*inv, v[3]*inv };
  float4 ob = { v[4]*inv, v[5]*inv, v[6]*inv, v[7]*inv };
  *(float4*)op = oa;
  *(float4*)(op + 4) = ob;
}

// ---------------------------------------------------------------------------
extern "C" void kernel_launch(void* const* d_in, const int* in_sizes, int n_in,
                              void* d_out, int out_size, void* d_ws, size_t ws_size,
                              hipStream_t stream)
{
  const float* x    = (const float*)d_in[0];
  const float* Wih0 = (const float*)d_in[1];
  const float* Whh0 = (const float*)d_in[2];
  const float* bih0 = (const float*)d_in[3];
  const float* bhh0 = (const float*)d_in[4];
  const float* Wih1 = (const float*)d_in[5];
  const float* Whh1 = (const float*)d_in[6];
  const float* bih1 = (const float*)d_in[7];
  const float* bhh1 = (const float*)d_in[8];
  const float* W1   = (const float*)d_in[9];
  const float* b1   = (const float*)d_in[10];
  const float* W1b  = (const float*)d_in[11];
  const float* b1b  = (const float*)d_in[12];
  const float* W2   = (const float*)d_in[13];
  const float* b2   = (const float*)d_in[14];
  const float* W2b  = (const float*)d_in[15];
  const float* b2b  = (const float*)d_in[16];
  (void)in_sizes; (void)n_in;

  const size_t HP  = (size_t)32 * 2048 * 256 * 4;   // packed history: 64MB
  const size_t XT  = (size_t)32 * 2048 * 64 * 4;    // packed x: 16.8MB
  const size_t WF  = (size_t)2 * 32 * 16 * 2 * 64 * 16;

  auto need = [&](int c) -> size_t {
    return (size_t)32 * c * 1024 * 4 + 2 * HP + XT + WF + (2u << 20);
  };
  int cs = 1024;
  while (cs > 512 && need(cs) > ws_size) cs >>= 1;
  if (need(cs) > ws_size) {
    hipMemsetAsync(d_out, 0x7F, (size_t)out_size * 4, stream);
    return;
  }

  char* w = (char*)d_ws;
  size_t off = 0;
  auto take = [&](size_t bytes) {
    size_t r = off;
    off = (off + bytes + 255) & ~(size_t)255;
    return r;
  };
  size_t o_xg   = take((size_t)32 * cs * 1024 * 4);
  size_t o_h0p  = take(HP);
  size_t o_h1p  = take(HP);
  size_t o_xp   = take(XT);
  size_t o_wf   = take(WF);
  size_t o_hp   = take(2 * 32768 * 4);   // 2 layers x 4 bufs x 32 x 256
  size_t o_flg  = take(2 * 512 * 4);
  size_t o_bias = take(8192);
  size_t o_cbuf = take(32 * 256 * 4);
  size_t o_clm  = take(8 * 32 * 4);

  float* xg    = (float*)(w + o_xg);
  u32*   h0p   = (u32*)(w + o_h0p);
  u32*   h1p   = (u32*)(w + o_h1p);
  u32*   xp    = (u32*)(w + o_xp);
  u32*   wf    = (u32*)(w + o_wf);
  u32*   hp    = (u32*)(w + o_hp);
  u32*   flg   = (u32*)(w + o_flg);
  float* biasc = (float*)(w + o_bias);
  float* cbuf  = (float*)(w + o_cbuf);
  u32*   clms  = (u32*)(w + o_clm);
  // overlays (dead regions at head time)
  const size_t PB = 17825792;   // 17MB slot
  float* P0    = (float*)(w + o_h0p);
  float* P1    = (float*)(w + o_h0p + PB);
  float* predT = (float*)(w + o_h0p + 2 * PB);
  float* out1  = (float*)(w + o_xg);
  float* out2  = (float*)(w + o_xg + PB);

  k_prep<<<513, 256, 0, stream>>>(Whh0, Whh1, bih0, bhh0, bih1, bhh1,
                                  wf, biasc, hp, flg, clms);
  k_packx<<<dim3(32, 32), 256, 0, stream>>>(x, xp);

  const int Q = 2048 / cs;
  int li = 0;
  for (int qq = 0; qq < Q; ++qq) {
    k_gemm<128, 128, 8, 8, 0, 1><<<dim3(cs / 128, 8, 32), 256, 0, stream>>>(
        nullptr, xp, Wih0, biasc, xg, xg,
        64, 64, 2048, (long)qq * cs, cs, 1024);
    k_scan<<<256, 256, 0, stream>>>(wf, xg, hp, flg, cbuf, h0p,
                                    clms + (li++) * 32,
                                    qq * cs, (qq + 1) * cs, cs);
  }
  for (int qq = 0; qq < Q; ++qq) {
    k_gemm<128, 128, 8, 8, 0, 1><<<dim3(cs / 128, 8, 32), 256, 0, stream>>>(
        nullptr, h0p, Wih1, biasc + 1024, xg, xg,
        256, 256, 2048, (long)qq * cs, cs, 1024);
    k_scan<<<256, 256, 0, stream>>>(wf + (size_t)32 * 16 * 2 * 64 * 4, xg,
                                    hp + 32768, flg + 512, cbuf, h1p,
                                    clms + (li++) * 32,
                                    qq * cs, (qq + 1) * cs, cs);
  }
  // heads
  k_gemm<128, 64, 8, 4, 1, 1><<<dim3(512, 1, 1), 256, 0, stream>>>(
      nullptr, h1p, W1, b1, P0, P0, 256, 256, 0, 0, 0, 64);
  k_gemm<128, 64, 8, 4, 2, 0><<<dim3(512, 1, 1), 256, 0, stream>>>(
      P0, nullptr, W1b, b1b, P0, P1, 64, 64, 0, 0, 0, 64);
  k_transP<<<dim3(32, 32), 256, 0, stream>>>(P1, predT);
  k_gemm<128, 128, 8, 8, 0, 0><<<dim3(16, 16, 1), 256, 0, stream>>>(
      predT, nullptr, W2, b2, out1, out1, 2048, 2048, 0, 0, 0, 2048);
  k_gemm<128, 128, 8, 8, 2, 0><<<dim3(16, 16, 1), 256, 0, stream>>>(
      out1, nullptr, W2b, b2b, out1, out2, 2048, 2048, 0, 0, 0, 2048);
  k_softmax<<<2048, 256, 0, stream>>>(out2, (float*)d_out);
}

// Round 5
// 38615.204 us; speedup vs baseline: 186.2305x; 1.2124x over previous
//
// LSTM_45337674776685 — R5: sound 2-group pipelined scan.
// R4 post-mortem: asm-invisible in-flight loads let regalloc reuse the
// destination VGPRs -> late writeback corrupts addresses -> GPU fault.
// R5 keeps the (correct) tag-in-data MALL protocol but all cross-CU loads are
// compiler-visible __hip_atomic_load(RELAXED, AGENT) u64s (sc1, tracked
// waitcnt, spill-safe). 4-slot rotating h buffer + 2-bit tag (hi16|lo14|tag2);
// tag mismatch -> guarded re-issue. Batch 32 split in two 16-row groups at
// alternating phases so one group's compute hides the other's MALL latency.
// 32 wgs x 2 waves (K-half each; verified R1 32x32 fragment layouts, A rows
// 16-31 duplicate 0-15). Raw s_barrier + lgkmcnt-only waits (no vmcnt drain).

#include <hip/hip_runtime.h>
#include <stdint.h>

typedef unsigned short u16;
typedef unsigned int   u32;
typedef unsigned long long u64;

typedef short  bf16x8 __attribute__((ext_vector_type(8)));
typedef float  f32x16 __attribute__((ext_vector_type(16)));

#define DEVI static __device__ __forceinline__

DEVI u16 f2bf(float x) {
  u32 u = __float_as_uint(x);
  u += 0x7FFFu + ((u >> 16) & 1u);
  return (u16)(u >> 16);
}
DEVI float bf2f(u16 h) { return __uint_as_float(((u32)h) << 16); }

DEVI float sig_fast(float x) {
  float d = 1.f + __expf(-x);
  float r = __builtin_amdgcn_rcpf(d);
  return r * (2.f - d * r);
}
DEVI float silu_f(float x) { return x * sig_fast(x); }

// workgroup barrier WITHOUT vmcnt drain: LDS ordering only, keeps the
// cross-phase prefetch loads in flight (guide T3 pattern).
DEVI void wg_barrier() {
  asm volatile("s_waitcnt lgkmcnt(0)" ::: "memory");
  __builtin_amdgcn_s_barrier();
  asm volatile("" ::: "memory");
  __builtin_amdgcn_sched_barrier(0);
}

// ---------------------------------------------------------------------------
// prep: W_hh0/1 -> MFMA B-fragments (blocks 0-255); hp tag init=2 (256-511);
// combined biases (512). Runs every launch.
// ---------------------------------------------------------------------------
__global__ void k_prep(const float* __restrict__ Whh0, const float* __restrict__ Whh1,
                       const float* __restrict__ bih0, const float* __restrict__ bhh0,
                       const float* __restrict__ bih1, const float* __restrict__ bhh1,
                       u32* __restrict__ wf, float* __restrict__ biasc,
                       u32* __restrict__ hp)
{
  if (blockIdx.x < 256) {
    int g = blockIdx.x * 256 + threadIdx.x;
    int layer = g >> 15;
    int nt = (g >> 10) & 31;
    int kt = (g >> 6) & 15;
    int l  = g & 63;
    int rr = l & 31, gate = rr & 3, jj = rr >> 2;
    int r  = gate * 256 + nt * 8 + jj;
    int k0 = kt * 16 + (l >> 5) * 8;
    const float* W = layer ? Whh1 : Whh0;
    float v[8];
    #pragma unroll
    for (int e = 0; e < 8; ++e) v[e] = W[(size_t)r * 256 + k0 + e];
    u32 hid[4], lod[4];
    #pragma unroll
    for (int p = 0; p < 4; ++p) {
      u16 h0 = f2bf(v[2 * p]), h1 = f2bf(v[2 * p + 1]);
      float l0 = v[2 * p] - bf2f(h0), l1 = v[2 * p + 1] - bf2f(h1);
      hid[p] = (u32)h0 | ((u32)h1 << 16);
      lod[p] = (u32)f2bf(l0) | ((u32)f2bf(l1) << 16);
    }
    size_t hoff = ((((size_t)(layer * 32 + nt) * 16 + kt) * 2 + 0) * 64 + l) * 4;
    size_t loff = hoff + 64 * 4;
    *(uint4*)(wf + hoff) = make_uint4(hid[0], hid[1], hid[2], hid[3]);
    *(uint4*)(wf + loff) = make_uint4(lod[0], lod[1], lod[2], lod[3]);
  } else if (blockIdx.x < 512) {
    // hp: 2 layers x 4 slots x 32 x 256 = 65536 u32. init tag = 2
    // (slots 1-3 first wanted tag 0, slot 0 first wanted tag 1 -> 2 is safe;
    // stale tags from h(t-4) are et-1 mod 4 != et -> always detectable).
    int idx = (blockIdx.x - 256) * 256 + threadIdx.x;
    hp[idx] = 2u;
  } else {
    int t = threadIdx.x;
    for (int i = t; i < 1024; i += 256) {
      biasc[i]        = bih0[i] + bhh0[i];
      biasc[1024 + i] = bih1[i] + bhh1[i];
    }
  }
}

// ---------------------------------------------------------------------------
// pack x (B,F,S) -> transposed packed u32 (B,S,F): (hi<<16)|lo
// ---------------------------------------------------------------------------
__global__ void k_packx(const float* __restrict__ x, u32* __restrict__ xp)
{
  __shared__ float tile[64][65];
  const int s0 = blockIdx.x * 64;
  const int b  = blockIdx.y;
  const int t  = threadIdx.x;
  {
    int ss = t & 63, fq = t >> 6;
    #pragma unroll
    for (int r = 0; r < 16; ++r) {
      int f = fq * 16 + r;
      tile[f][ss] = x[((size_t)b * 64 + f) * 2048 + s0 + ss];
    }
  }
  __syncthreads();
  {
    int f2 = t & 63, sq = t >> 6;
    #pragma unroll
    for (int r = 0; r < 16; ++r) {
      int s = sq * 16 + r;
      float v = tile[f2][s];
      u16 hi = f2bf(v);
      u16 lo = f2bf(v - bf2f(hi));
      xp[((size_t)b * 2048 + s0 + s) * 64 + f2] = ((u32)hi << 16) | lo;
    }
  }
}

// ---------------------------------------------------------------------------
// transpose P1 (B,S,64) f32 -> predT (B,64,S) f32
// ---------------------------------------------------------------------------
__global__ void k_transP(const float* __restrict__ P, float* __restrict__ PT)
{
  __shared__ float tile[64][65];
  const int s0 = blockIdx.x * 64;
  const int b  = blockIdx.y;
  const int t  = threadIdx.x;
  {
    int f = t & 63, sq = t >> 6;
    #pragma unroll
    for (int r = 0; r < 16; ++r) {
      int s = sq * 16 + r;
      tile[s][f] = P[((size_t)b * 2048 + s0 + s) * 64 + f];
    }
  }
  __syncthreads();
  {
    int s2 = t & 63, fq = t >> 6;
    #pragma unroll
    for (int r = 0; r < 16; ++r) {
      int ff = fq * 16 + r;
      PT[((size_t)b * 64 + ff) * 2048 + s0 + s2] = tile[s2][ff];
    }
  }
}

// ---------------------------------------------------------------------------
// generic fp32 TN GEMM. UA: A is packed u32 (hi<<16|lo), value = hi + lo.
// MODE 0: +bias ; 1: silu(+bias) ; 2: res + silu(+bias)
// ---------------------------------------------------------------------------
template<int BM, int BN, int TM, int TN, int MODE, int UA>
__global__ __launch_bounds__(256) void k_gemm(
    const float* __restrict__ Af,
    const u32* __restrict__ Ap,
    const float* __restrict__ Bw,
    const float* __restrict__ bias,
    const float* __restrict__ res,
    float* __restrict__ C,
    int K, int lda,
    long a_zrows, long a_row0, long c_zrows, int ldc)
{
  constexpr int BK = 32;
  __shared__ float As[BK][BM + 4];
  __shared__ float Bs[BK][BN + 4];
  const int t  = threadIdx.x;
  const int tx = t & 15, ty = t >> 4;
  const int mb = blockIdx.x * BM, nb = blockIdx.y * BN;
  const long za = (long)blockIdx.z * a_zrows + a_row0 + mb;
  const long zc = (long)blockIdx.z * c_zrows + mb;

  float acc[TM][TN];
  #pragma unroll
  for (int i = 0; i < TM; ++i)
    #pragma unroll
    for (int jn = 0; jn < TN; ++jn) acc[i][jn] = 0.f;

  for (int k0 = 0; k0 < K; k0 += BK) {
    #pragma unroll
    for (int it = 0; it < BM * 8 / 256; ++it) {
      int idx = it * 256 + t;
      int row = idx >> 3, c4 = idx & 7;
      long ar = za + row;
      float v0, v1, v2, v3;
      if (UA) {
        uint4 qv = *(const uint4*)(Ap + (size_t)ar * lda + k0 + c4 * 4);
        v0 = bf2f((u16)(qv.x >> 16)) + bf2f((u16)(qv.x & 0xFFFFu));
        v1 = bf2f((u16)(qv.y >> 16)) + bf2f((u16)(qv.y & 0xFFFFu));
        v2 = bf2f((u16)(qv.z >> 16)) + bf2f((u16)(qv.z & 0xFFFFu));
        v3 = bf2f((u16)(qv.w >> 16)) + bf2f((u16)(qv.w & 0xFFFFu));
      } else {
        float4 f4 = *(const float4*)(Af + (size_t)ar * lda + k0 + c4 * 4);
        v0 = f4.x; v1 = f4.y; v2 = f4.z; v3 = f4.w;
      }
      As[c4 * 4 + 0][row] = v0;
      As[c4 * 4 + 1][row] = v1;
      As[c4 * 4 + 2][row] = v2;
      As[c4 * 4 + 3][row] = v3;
    }
    #pragma unroll
    for (int it = 0; it < BN * 8 / 256; ++it) {
      int idx = it * 256 + t;
      int row = idx >> 3, c4 = idx & 7;
      float4 f4 = *(const float4*)(Bw + (size_t)(nb + row) * K + k0 + c4 * 4);
      Bs[c4 * 4 + 0][row] = f4.x;
      Bs[c4 * 4 + 1][row] = f4.y;
      Bs[c4 * 4 + 2][row] = f4.z;
      Bs[c4 * 4 + 3][row] = f4.w;
    }
    __syncthreads();
    #pragma unroll
    for (int kk = 0; kk < BK; ++kk) {
      float av[TM], bv[TN];
      {
        float4 t0 = *(const float4*)&As[kk][ty * TM];
        av[0] = t0.x; av[1] = t0.y; av[2] = t0.z; av[3] = t0.w;
        if (TM == 8) {
          float4 t1 = *(const float4*)&As[kk][ty * TM + 4];
          av[4] = t1.x; av[5] = t1.y; av[6] = t1.z; av[7] = t1.w;
        }
      }
      {
        float4 t0 = *(const float4*)&Bs[kk][tx * TN];
        bv[0] = t0.x; bv[1] = t0.y; bv[2] = t0.z; bv[3] = t0.w;
        if (TN == 8) {
          float4 t1 = *(const float4*)&Bs[kk][tx * TN + 4];
          bv[4] = t1.x; bv[5] = t1.y; bv[6] = t1.z; bv[7] = t1.w;
        }
      }
      #pragma unroll
      for (int i = 0; i < TM; ++i)
        #pragma unroll
        for (int jn = 0; jn < TN; ++jn)
          acc[i][jn] = fmaf(av[i], bv[jn], acc[i][jn]);
    }
    __syncthreads();
  }
  #pragma unroll
  for (int i = 0; i < TM; ++i) {
    long crow = zc + ty * TM + i;
    float* cp = C + (size_t)crow * ldc + nb + tx * TN;
    const float* rp = res + (size_t)crow * ldc + nb + tx * TN;
    #pragma unroll
    for (int jn = 0; jn < TN; ++jn) {
      float v = acc[i][jn] + bias[nb + tx * TN + jn];
      if (MODE == 1) v = silu_f(v);
      else if (MODE == 2) v = rp[jn] + silu_f(v);
      cp[jn] = v;
    }
  }
}

// ---------------------------------------------------------------------------
// persistent LSTM scan: 32 wgs x 2 waves (wave = K-half kh). hp[4][32][256]
// u32 = (hi16|lo14|tag2), slot = t&3, tag = (t>>2)&3. Two batch groups
// (rows 0-15 / 16-31) at alternating phases; act wave for group G is wave G.
// All cross-CU traffic via compiler-visible agent atomics (sc1).
// ---------------------------------------------------------------------------
#define ISSUE(D, T, G)                                                       \
  do {                                                                       \
    const u32* p_ = hp + (((u32)(T)) & 3u) * 8192 + (G) * 4096 + abase;      \
    _Pragma("unroll")                                                        \
    for (int kt_ = 0; kt_ < 8; ++kt_) {                                      \
      _Pragma("unroll")                                                      \
      for (int m_ = 0; m_ < 4; ++m_)                                         \
        (D)[kt_ * 4 + m_] = __hip_atomic_load(                               \
            (const u64*)(p_ + kt_ * 16 + m_ * 2),                            \
            __ATOMIC_RELAXED, __HIP_MEMORY_SCOPE_AGENT);                     \
    }                                                                        \
    __builtin_amdgcn_sched_barrier(0);                                       \
  } while (0)

#define TAGRETRY(D, T, G)                                                    \
  do {                                                                       \
    const u32 et_ = (((u32)(T)) >> 2) & 3u;                                  \
    int att_ = 0;                                                            \
    while (true) {                                                           \
      u32 orv_ = 0;                                                          \
      _Pragma("unroll")                                                      \
      for (int i_ = 0; i_ < 32; ++i_)                                        \
        orv_ |= ((u32)(D)[i_] ^ et_) | ((u32)((D)[i_] >> 32) ^ et_);         \
      if (__all((int)((orv_ & 3u) == 0u))) break;                            \
      if (++att_ > 4096) break;                                              \
      ISSUE(D, T, G);                                                        \
    }                                                                        \
  } while (0)

#define ACTSTORE(G, ACC, PH, XGV, T)                                         \
  do {                                                                       \
    _Pragma("unroll")                                                        \
    for (int reg_ = 0; reg_ < 8; ++reg_) {                                   \
      float pre_ = (ACC)[reg_] + racc[PH][l][reg_] + (XGV)[reg_];            \
      float s_ = isg ? (2.f * pre_) : pre_;                                  \
      float y_ = sig_fast(s_);                                               \
      zex[kh][hi5][reg_][rr] = isg ? (2.f * y_ - 1.f) : y_;                  \
    }                                                                        \
    if (q < 2) {                                                             \
      const u32 tg_ = (((u32)((T) + 1)) >> 2) & 3u;                          \
      u32* dst_ = hp + (((u32)((T) + 1)) & 3u) * 8192;                       \
      _Pragma("unroll")                                                      \
      for (int ri_ = 0; ri_ < 4; ++ri_) {                                    \
        const float4 gv_ = *(const float4*)&zex[kh][hi5][q * 4 + ri_][jj * 4]; \
        float cn_ = fmaf(gv_.y, c4v[ri_], gv_.x * gv_.z);                    \
        c4v[ri_] = cn_;                                                      \
        float th_ = 2.f * sig_fast(2.f * cn_) - 1.f;                         \
        float hv_ = gv_.w * th_;                                             \
        u16 sh_ = f2bf(hv_);                                                 \
        u16 sl_ = f2bf(hv_ - bf2f(sh_));                                     \
        int b_ = (G) * 16 + 8 * q + 4 * hi5 + ri_;                           \
        __hip_atomic_store(dst_ + (size_t)b_ * 256 + j,                      \
                           ((u32)sh_ << 16) | ((u32)sl_ & 0xFFFCu) | tg_,    \
                           __ATOMIC_RELAXED, __HIP_MEMORY_SCOPE_AGENT);      \
        __builtin_nontemporal_store(((u32)sh_ << 16) | (u32)sl_,             \
            histp + ((size_t)b_ * 2048 + (T)) * 256 + j);                    \
      }                                                                      \
    }                                                                        \
  } while (0)

DEVI void mfma_half(const u64 (&d)[32], const bf16x8 (&wh)[8], const bf16x8 (&wl)[8],
                    f32x16& a1, f32x16& a2)
{
  #pragma unroll
  for (int kk = 0; kk < 8; ++kk) {
    u32 e0 = (u32)d[kk*4+0], e1 = (u32)(d[kk*4+0] >> 32);
    u32 e2 = (u32)d[kk*4+1], e3 = (u32)(d[kk*4+1] >> 32);
    u32 e4 = (u32)d[kk*4+2], e5 = (u32)(d[kk*4+2] >> 32);
    u32 e6 = (u32)d[kk*4+3], e7 = (u32)(d[kk*4+3] >> 32);
    union { uint4 u; bf16x8 v; } ua, ub;
    ua.u = make_uint4(__builtin_amdgcn_perm(e1, e0, 0x07060302u),
                      __builtin_amdgcn_perm(e3, e2, 0x07060302u),
                      __builtin_amdgcn_perm(e5, e4, 0x07060302u),
                      __builtin_amdgcn_perm(e7, e6, 0x07060302u));
    ub.u = make_uint4(__builtin_amdgcn_perm(e1, e0, 0x05040100u) & 0xFFFCFFFCu,
                      __builtin_amdgcn_perm(e3, e2, 0x05040100u) & 0xFFFCFFFCu,
                      __builtin_amdgcn_perm(e5, e4, 0x05040100u) & 0xFFFCFFFCu,
                      __builtin_amdgcn_perm(e7, e6, 0x05040100u) & 0xFFFCFFFCu);
    a1 = __builtin_amdgcn_mfma_f32_32x32x16_bf16(ua.v, wh[kk], a1, 0, 0, 0);
    a1 = __builtin_amdgcn_mfma_f32_32x32x16_bf16(ub.v, wh[kk], a1, 0, 0, 0);
    a2 = __builtin_amdgcn_mfma_f32_32x32x16_bf16(ua.v, wl[kk], a2, 0, 0, 0);
  }
}

__global__ __launch_bounds__(128) void k_scan(
    const u32* __restrict__ wf,
    const float* __restrict__ xg,          // [B][cs][1024]
    u32* __restrict__ hp,                  // [4][32][256]
    float* __restrict__ cbuf,              // [32][256]
    u32* __restrict__ histp,               // [B][2048][256]
    int t0, int t1, int cs)
{
  const int kh = threadIdx.x >> 6;        // K-half (wave id) == act group
  const int l  = threadIdx.x & 63;
  const int nt = blockIdx.x;

  const int rr  = l & 31;
  const int hi5 = l >> 5;
  const int gate = rr & 3;
  const int jj   = rr >> 2;
  const int q    = l & 3;
  const int j    = nt * 8 + jj;
  const int rorig = gate * 256 + nt * 8 + jj;
  const bool isg = (gate == 2);
  const u32 abase = (u32)(l & 15) * 256 + (u32)kh * 128 + (u32)hi5 * 8;

  // register-resident weight fragments: this wave's K-half of tile nt
  bf16x8 wh[8], wl[8];
  {
    const u32* p = wf + (size_t)nt * (16 * 2 * 64 * 4);
    #pragma unroll
    for (int kk = 0; kk < 8; ++kk) {
      int kt = kh * 8 + kk;
      union { uint4 u; bf16x8 v; } ua, ub;
      ua.u = *(const uint4*)(p + ((size_t)(kt * 2 + 0) * 64 + l) * 4);
      ub.u = *(const uint4*)(p + ((size_t)(kt * 2 + 1) * 64 + l) * 4);
      wh[kk] = ua.v; wl[kk] = ub.v;
    }
  }

  float c4v[4] = {0.f, 0.f, 0.f, 0.f};
  if (t0 > 0 && q < 2) {
    #pragma unroll
    for (int ri = 0; ri < 4; ++ri)
      c4v[ri] = cbuf[(size_t)(kh * 16 + 8 * q + 4 * hi5 + ri) * 256 + j];
  }

  __shared__ float racc[2][64][9];
  __shared__ __align__(16) float zex[2][2][8][40];

  u64 d0[32], d1[32];

  if (t0 > 0) ISSUE(d0, t0, 0);

  for (int t = t0; t < t1; ++t) {
    // ---------------- phase A: group 0, act wave 0 ----------------
    if (t > 0) ISSUE(d1, t, 1);           // prefetch G1 h(t)
    float xgv0[8];
    if (kh == 0) {
      #pragma unroll
      for (int reg = 0; reg < 8; ++reg) {
        int b = (reg & 3) + 8 * (reg >> 2) + 4 * hi5;
        xgv0[reg] = __builtin_nontemporal_load(
            xg + ((size_t)b * cs + (t - t0)) * 1024 + rorig);
      }
    }
    f32x16 pA = {}, qA = {};
    if (t > 0) {
      TAGRETRY(d0, t, 0);
      mfma_half(d0, wh, wl, pA, qA);
    }
    f32x16 accA = pA + qA;
    if (kh == 1) {
      #pragma unroll
      for (int i = 0; i < 8; ++i) racc[0][l][i] = accA[i];
    }
    wg_barrier();
    if (kh == 0) ACTSTORE(0, accA, 0, xgv0, t);

    // ---------------- phase B: group 1, act wave 1 ----------------
    if (t + 1 < t1) ISSUE(d0, t + 1, 0);  // prefetch G0 h(t+1)
    float xgv1[8];
    if (kh == 1) {
      #pragma unroll
      for (int reg = 0; reg < 8; ++reg) {
        int b = 16 + (reg & 3) + 8 * (reg >> 2) + 4 * hi5;
        xgv1[reg] = __builtin_nontemporal_load(
            xg + ((size_t)b * cs + (t - t0)) * 1024 + rorig);
      }
    }
    f32x16 pB = {}, qB = {};
    if (t > 0) {
      TAGRETRY(d1, t, 1);
      mfma_half(d1, wh, wl, pB, qB);
    }
    f32x16 accB = pB + qB;
    if (kh == 0) {
      #pragma unroll
      for (int i = 0; i < 8; ++i) racc[1][l][i] = accB[i];
    }
    wg_barrier();
    if (kh == 1) ACTSTORE(1, accB, 1, xgv1, t);
  }

  if (q < 2) {
    #pragma unroll
    for (int ri = 0; ri < 4; ++ri)
      cbuf[(size_t)(kh * 16 + 8 * q + 4 * hi5 + ri) * 256 + j] = c4v[ri];
  }
}

// ---------------------------------------------------------------------------
// softmax over rows of 2048
// ---------------------------------------------------------------------------
__global__ __launch_bounds__(256) void k_softmax(const float* __restrict__ X,
                                                 float* __restrict__ O)
{
  __shared__ float red[256];
  const int t = threadIdx.x;
  const size_t row = blockIdx.x;
  const float* xr = X + row * 2048;
  float v[8];
  {
    float4 va = *(const float4*)(xr + t * 8);
    float4 vb = *(const float4*)(xr + t * 8 + 4);
    v[0]=va.x; v[1]=va.y; v[2]=va.z; v[3]=va.w;
    v[4]=vb.x; v[5]=vb.y; v[6]=vb.z; v[7]=vb.w;
  }
  float m = v[0];
  #pragma unroll
  for (int i = 1; i < 8; ++i) m = fmaxf(m, v[i]);
  red[t] = m; __syncthreads();
  for (int s = 128; s > 0; s >>= 1) {
    if (t < s) red[t] = fmaxf(red[t], red[t + s]);
    __syncthreads();
  }
  m = red[0];
  __syncthreads();
  float sum = 0.f;
  #pragma unroll
  for (int i = 0; i < 8; ++i) { v[i] = __expf(v[i] - m); sum += v[i]; }
  red[t] = sum; __syncthreads();
  for (int s = 128; s > 0; s >>= 1) {
    if (t < s) red[t] += red[t + s];
    __syncthreads();
  }
  const float inv = 1.f / red[0];
  float* op = O + row * 2048 + t * 8;
  float4 oa = { v[0]*inv, v[1]*inv, v[2]*inv, v[3]*inv };
  float4 ob = { v[4]*inv, v[5]*inv, v[6]*inv, v[7]*inv };
  *(float4*)op = oa;
  *(float4*)(op + 4) = ob;
}

// ---------------------------------------------------------------------------
extern "C" void kernel_launch(void* const* d_in, const int* in_sizes, int n_in,
                              void* d_out, int out_size, void* d_ws, size_t ws_size,
                              hipStream_t stream)
{
  const float* x    = (const float*)d_in[0];
  const float* Wih0 = (const float*)d_in[1];
  const float* Whh0 = (const float*)d_in[2];
  const float* bih0 = (const float*)d_in[3];
  const float* bhh0 = (const float*)d_in[4];
  const float* Wih1 = (const float*)d_in[5];
  const float* Whh1 = (const float*)d_in[6];
  const float* bih1 = (const float*)d_in[7];
  const float* bhh1 = (const float*)d_in[8];
  const float* W1   = (const float*)d_in[9];
  const float* b1   = (const float*)d_in[10];
  const float* W1b  = (const float*)d_in[11];
  const float* b1b  = (const float*)d_in[12];
  const float* W2   = (const float*)d_in[13];
  const float* b2   = (const float*)d_in[14];
  const float* W2b  = (const float*)d_in[15];
  const float* b2b  = (const float*)d_in[16];
  (void)in_sizes; (void)n_in;

  const size_t HP  = (size_t)32 * 2048 * 256 * 4;   // packed history: 64MB
  const size_t XT  = (size_t)32 * 2048 * 64 * 4;    // packed x: 16.8MB
  const size_t WF  = (size_t)2 * 32 * 16 * 2 * 64 * 16;

  auto need = [&](int c) -> size_t {
    return (size_t)32 * c * 1024 * 4 + 2 * HP + XT + WF + (4u << 20);
  };
  int cs = 2048;
  while (cs > 512 && need(cs) > ws_size) cs >>= 1;
  if (need(cs) > ws_size) {
    hipMemsetAsync(d_out, 0x7F, (size_t)out_size * 4, stream);
    return;
  }

  char* w = (char*)d_ws;
  size_t off = 0;
  auto take = [&](size_t bytes) {
    size_t r = off;
    off = (off + bytes + 255) & ~(size_t)255;
    return r;
  };
  size_t o_xg   = take((size_t)32 * cs * 1024 * 4);
  size_t o_h0p  = take(HP);
  size_t o_h1p  = take(HP);
  size_t o_xp   = take(XT);
  size_t o_wf   = take(WF);
  size_t o_hp   = take(2 * 32768 * 4);   // 2 layers x 4 slots x 32 x 256
  size_t o_bias = take(8192);
  size_t o_cbuf = take(32 * 256 * 4);

  float* xg    = (float*)(w + o_xg);
  u32*   h0p   = (u32*)(w + o_h0p);
  u32*   h1p   = (u32*)(w + o_h1p);
  u32*   xp    = (u32*)(w + o_xp);
  u32*   wf    = (u32*)(w + o_wf);
  u32*   hp    = (u32*)(w + o_hp);
  float* biasc = (float*)(w + o_bias);
  float* cbuf  = (float*)(w + o_cbuf);
  // overlays (dead regions at head time)
  const size_t PB = 17825792;   // 17MB slot
  float* P0    = (float*)(w + o_h0p);
  float* P1    = (float*)(w + o_h0p + PB);
  float* predT = (float*)(w + o_h0p + 2 * PB);
  float* out1  = (float*)(w + o_xg);
  float* out2  = (float*)(w + o_xg + PB);

  k_prep<<<513, 256, 0, stream>>>(Whh0, Whh1, bih0, bhh0, bih1, bhh1,
                                  wf, biasc, hp);
  k_packx<<<dim3(32, 32), 256, 0, stream>>>(x, xp);

  const int Q = 2048 / cs;
  for (int qq = 0; qq < Q; ++qq) {
    k_gemm<128, 128, 8, 8, 0, 1><<<dim3(cs / 128, 8, 32), 256, 0, stream>>>(
        nullptr, xp, Wih0, biasc, xg, xg,
        64, 64, 2048, (long)qq * cs, cs, 1024);
    k_scan<<<32, 128, 0, stream>>>(wf, xg, hp, cbuf, h0p,
                                   qq * cs, (qq + 1) * cs, cs);
  }
  for (int qq = 0; qq < Q; ++qq) {
    k_gemm<128, 128, 8, 8, 0, 1><<<dim3(cs / 128, 8, 32), 256, 0, stream>>>(
        nullptr, h0p, Wih1, biasc + 1024, xg, xg,
        256, 256, 2048, (long)qq * cs, cs, 1024);
    k_scan<<<32, 128, 0, stream>>>(wf + (size_t)32 * 16 * 2 * 64 * 4, xg,
                                   hp + 32768, cbuf, h1p,
                                   qq * cs, (qq + 1) * cs, cs);
  }
  // heads
  k_gemm<128, 64, 8, 4, 1, 1><<<dim3(512, 1, 1), 256, 0, stream>>>(
      nullptr, h1p, W1, b1, P0, P0, 256, 256, 0, 0, 0, 64);
  k_gemm<128, 64, 8, 4, 2, 0><<<dim3(512, 1, 1), 256, 0, stream>>>(
      P0, nullptr, W1b, b1b, P0, P1, 64, 64, 0, 0, 0, 64);
  k_transP<<<dim3(32, 32), 256, 0, stream>>>(P1, predT);
  k_gemm<128, 128, 8, 8, 0, 0><<<dim3(16, 16, 1), 256, 0, stream>>>(
      predT, nullptr, W2, b2, out1, out1, 2048, 2048, 0, 0, 0, 2048);
  k_gemm<128, 128, 8, 8, 2, 0><<<dim3(16, 16, 1), 256, 0, stream>>>(
      out1, nullptr, W2b, b2b, out1, out2, 2048, 2048, 0, 0, 0, 2048);
  k_softmax<<<2048, 256, 0, stream>>>(out2, (float*)d_out);
}